// Round 7
// baseline (380.144 us; speedup 1.0000x reference)
//
#include <hip/hip_runtime.h>
#include <cmath>

// Problem constants: S=16384, IN_DIM=1024, D=6400, BINS=20
#define S_DIM 16384
#define K_DIM 1024
#define D_DIM 6400
#define NBINS 20
#define HSTRIDE 21   // shist column stride (pad 20->21: spreads banks)

using half_t = _Float16;
using half8  = __attribute__((ext_vector_type(8))) _Float16;
using f32x4  = __attribute__((ext_vector_type(4))) float;

// ---------------- fp32 -> fp16 convert + d_out zeroing (one launch) -------
__global__ void cvt_f32_f16(const float* __restrict__ a, half_t* __restrict__ da, int n8a,
                            const float* __restrict__ b, half_t* __restrict__ db, int n8b,
                            float4* __restrict__ z, int nz4) {
  int i = blockIdx.x * blockDim.x + threadIdx.x;
  if (i < nz4) z[i] = (float4){0.f, 0.f, 0.f, 0.f};   // histogram accumulator
  const float* s; half_t* d; int idx;
  if (i < n8a) { s = a; d = da; idx = i; }
  else { idx = i - n8a; if (idx >= n8b) return; s = b; d = db; }
  float4 v0 = ((const float4*)s)[idx * 2];
  float4 v1 = ((const float4*)s)[idx * 2 + 1];
  half8 h = { (half_t)v0.x, (half_t)v0.y, (half_t)v0.z, (half_t)v0.w,
              (half_t)v1.x, (half_t)v1.y, (half_t)v1.z, (half_t)v1.w };
  ((half8*)d)[idx] = h;
}

#define VMWAIT(N) __asm__ volatile("s_waitcnt vmcnt(" #N ")" ::: "memory")
#define BAR()     __asm__ volatile("s_barrier" ::: "memory")
#define SP1()     __builtin_amdgcn_s_setprio(1)
#define SP0()     __builtin_amdgcn_s_setprio(0)

#define GLL(SRC, DST) __builtin_amdgcn_global_load_lds(                      \
    (const __attribute__((address_space(1))) void*)(SRC),                    \
    (__attribute__((address_space(3))) void*)(DST), 16, 0, 0)

// ------- fused GEMM + histogram, 256x256, 16-wave, 4-deep staging ---------
// 1024 threads = 16 waves (4M x 4N); per-wave C = 64x64; BK=32.
// R6 skeleton (read-ahead phases, 2 barriers/tile, conflict-free swizzle,
// refcheck-passing) with ONE change: staging pipeline deepened 2 -> 4
// buffers.  Rationale (R1/R3/R4/R6 post-mortem): all four structures pin at
// ~6 TB/s aggregate global-read delivery (bytes/dur identical across
// schedules), i.e. the DMA queue drains between per-tile bursts (in-flight
// ~16-32KB/CU < latency x BW ~65KB).  Staging t+4 at P3 keeps 6-8 GLL/wave
// in flight (~100KB/CU) so delivery runs continuously (m97 regime).
//
// Per tile t (buf PB = t%4, PN = (t+1)%4):
//   P0: read bHi(t)[PB]       ; MFMA Q00(aLo,bLo)
//   P1: read aHi(t)[PB]       ; MFMA Q01(aLo,bHi) ; W1; BAR
//   P2: read aLo(t+1)[PN]     ; MFMA Q11(aHi,bHi) ; W2; BAR
//   P3: stage {A,B}(t+4)->PB  ; MFMA Q10(aHi,bLo) ; read bLo(t+1)[PN]
// Ledger (issue order is monotone A(k),B(k) pairs; vmcnt retires oldest):
//   at t P1-end outstanding = {A,B}(t+1),(t+2),(t+3) = 6 -> W1=VMWAIT(5)
//   retires exactly A(t+1); after P2-end W2=VMWAIT(4) retires B(t+1);
//   P3 issues {A,B}(t+4) -> 6 again.  Barrier AFTER each wait publishes all
//   waves' contributions before the cross-wave read (RAW).  Never drains to
//   0 until the tail (t=30).
// WAR: stage into buf[t%4] at P3; last read of that buffer is aHi@P1,
// MFMA-consumed (lgkm-drained) before the P2-end barrier -> safe.
// Tail: t=28 W1/W2=5/4 (no stage), t=29 3/2, t=30 1/0, t=31 none.
// LDS swizzle (64B rows, 4x16B chunks): reader chunk = quad ^ ((l16>>1)&3);
// staging inverse on the GLOBAL source (g = (t&3)^((t>>3)&3)); GLL dest
// linear (both-sides-or-neither).  Measured conflict-free (counter = hist
// floor 8567313 in R6).
__global__ __launch_bounds__(1024, 4) void gemm_hist256(
    const half_t* __restrict__ xh, const half_t* __restrict__ wh,
    const float* __restrict__ mins, const float* __restrict__ maxs,
    int* __restrict__ ghist)
{
  __shared__ __align__(16) char ldsA[4 * 16384];   // 4 bufs x 256 rows x 64 B
  __shared__ __align__(16) char ldsB[4 * 16384];
  __shared__ int shist[256 * HSTRIDE];             // 21.5 KB  (total 152.6 KB)

  const int t    = threadIdx.x;
  const int lane = t & 63;
  const int wv   = t >> 6;           // 0..15
  const int wm   = wv >> 2;          // 0..3
  const int wn   = wv & 3;           // 0..3
  const int l16  = lane & 15;
  const int quad = lane >> 4;

  // XCD-aware bijective swizzle: 1600 blocks = 8 XCDs x 200
  const int bid = blockIdx.x;
  const int wg  = (bid & 7) * 200 + (bid >> 3);
  const int ct  = wg / 64;                 // 0..24 col-tiles
  const int rt  = wg - ct * 64;            // 0..63 row-tiles
  const int colBase = ct * 256;
  const int rowBase = rt * 256;

  for (int i = t; i < 256 * HSTRIDE; i += 1024) shist[i] = 0;

  // Fragment read bases. Row = (wm|wn)*64 + f*16 + l16; swizzled chunk =
  // quad ^ ((row>>1)&3) = quad ^ ((l16>>1)&3).
  const int swz = (quad ^ ((l16 >> 1) & 3)) * 16;
  const char* pA = ldsA + (wm * 64 + l16) * 64 + swz;
  const char* pB = ldsB + (wn * 64 + l16) * 64 + swz;

  // Staging: thread t owns linear slot (row r0 = t>>2, chunk t&3) = byte
  // t*16; fetches global chunk g = (t&3)^((r0>>1)&3) = (t&3)^((t>>3)&3).
  const int r0   = t >> 2;                                   // 0..255
  const int gOff = r0 * K_DIM + (((t & 3) ^ ((t >> 3) & 3)) * 8);  // elements
  const int wvD  = wv * 1024;   // wave-uniform LDS base (HW adds lane*16)

  const half_t* xS = xh + (size_t)rowBase * K_DIM + gOff;
  const half_t* wS = wh + (size_t)colBase * K_DIM + gOff;

  f32x4 acc[4][4];
#pragma unroll
  for (int m = 0; m < 4; ++m)
#pragma unroll
    for (int n = 0; n < 4; ++n) acc[m][n] = (f32x4){0.f, 0.f, 0.f, 0.f};

  half8 aLo[2], aHi[2], bLo[2], bHi[2];

#define MFMA4(AH, BH, MO, NO)                                                \
  _Pragma("unroll") for (int m2 = 0; m2 < 2; ++m2)                           \
  _Pragma("unroll") for (int n2 = 0; n2 < 2; ++n2)                           \
    acc[(MO) + m2][(NO) + n2] = __builtin_amdgcn_mfma_f32_16x16x32_f16(      \
        AH[m2], BH[n2], acc[(MO) + m2][(NO) + n2], 0, 0, 0);

  // Prologue: stage tiles 0..3 into bufs 0..3 (A,B pairs, monotone order);
  // VMWAIT(6) retires {A,B}(0) (keeps 6 in flight); BAR publishes; preload.
  GLL(xS,      ldsA + wvD);          GLL(wS,      ldsB + wvD);
  GLL(xS + 32, ldsA + 16384 + wvD);  GLL(wS + 32, ldsB + 16384 + wvD);
  GLL(xS + 64, ldsA + 32768 + wvD);  GLL(wS + 64, ldsB + 32768 + wvD);
  GLL(xS + 96, ldsA + 49152 + wvD);  GLL(wS + 96, ldsB + 49152 + wvD);
  VMWAIT(6); BAR();
  aLo[0] = *(const half8*)(pA);  aLo[1] = *(const half8*)(pA + 1024);
  bLo[0] = *(const half8*)(pB);  bLo[1] = *(const half8*)(pB + 1024);

  // Loop-carried staging pointers: at tile TT they point at k-offset
  // (TT+4)*32 elements (tile TT stages tile TT+4); advance +32 per tile.
  const half_t* xStg = xS + 128;
  const half_t* wStg = wS + 128;

  // PB = current tile's buffer offset, PN = next tile's.
#define TILE(PB, PN, RDA, RDB, STG, W1A, W2A)                                \
  {                                                                          \
    bHi[0] = *(const half8*)(pB + (PB) + 2048);                              \
    bHi[1] = *(const half8*)(pB + (PB) + 3072);                              \
    SP1(); MFMA4(aLo, bLo, 0, 0); SP0();                                     \
    aHi[0] = *(const half8*)(pA + (PB) + 2048);                              \
    aHi[1] = *(const half8*)(pA + (PB) + 3072);                              \
    SP1(); MFMA4(aLo, bHi, 0, 2); SP0();                                     \
    W1A; BAR();                                                              \
    if (RDA) {                                                               \
      aLo[0] = *(const half8*)(pA + (PN));                                   \
      aLo[1] = *(const half8*)(pA + (PN) + 1024);                            \
    }                                                                        \
    SP1(); MFMA4(aHi, bHi, 2, 2); SP0();                                     \
    W2A; BAR();                                                              \
    if (STG) {                                                               \
      GLL(xStg, ldsA + (PB) + wvD);                                          \
      GLL(wStg, ldsB + (PB) + wvD);                                          \
      xStg += 32; wStg += 32;                                                \
    }                                                                        \
    SP1(); MFMA4(aHi, bLo, 2, 0); SP0();                                     \
    if (RDB) {                                                               \
      bLo[0] = *(const half8*)(pB + (PN));                                   \
      bLo[1] = *(const half8*)(pB + (PN) + 1024);                            \
    }                                                                        \
  }

  // Tiles 0..27 (7 iterations x 4, buffer parities compile-time).
#pragma unroll 1
  for (int it = 0; it < 7; ++it) {
    TILE(0,     16384, 1, 1, 1, VMWAIT(5), VMWAIT(4));
    TILE(16384, 32768, 1, 1, 1, VMWAIT(5), VMWAIT(4));
    TILE(32768, 49152, 1, 1, 1, VMWAIT(5), VMWAIT(4));
    TILE(49152, 0,     1, 1, 1, VMWAIT(5), VMWAIT(4));
  }
  // Tail: nothing left to stage; counted waits shrink to drain.
  TILE(0,     16384, 1, 1, 0, VMWAIT(5), VMWAIT(4));   // t=28
  TILE(16384, 32768, 1, 1, 0, VMWAIT(3), VMWAIT(2));   // t=29
  TILE(32768, 49152, 1, 1, 0, VMWAIT(1), VMWAIT(0));   // t=30
  TILE(49152, 0,     0, 0, 0, (void)0,   (void)0);     // t=31

#undef TILE

  // Epilogue: bin 64 values/thread. torch.histc semantics: count iff
  // min<=v<=max; v==max -> last bin (trunc==floor since v-a>=0).
#pragma unroll
  for (int nf = 0; nf < 4; ++nf) {
    const int lc = wn * 64 + nf * 16 + l16;
    const float a = mins[colBase + lc], b = maxs[colBase + lc];
    const float sc = (float)NBINS / (b - a);
    int* colHist = &shist[lc * HSTRIDE];
#pragma unroll
    for (int mf = 0; mf < 4; ++mf) {
#pragma unroll
      for (int r = 0; r < 4; ++r) {
        float v = acc[mf][nf][r];
        if (v >= a && v <= b) {
          int bin = (int)((v - a) * sc);
          bin = bin > NBINS - 1 ? NBINS - 1 : bin;
          atomicAdd(&colHist[bin], 1);
        }
      }
    }
  }
  __syncthreads();
  for (int i = t; i < 256 * NBINS; i += 1024) {
    int col = i / NBINS, bin = i - col * NBINS;
    int v = shist[col * HSTRIDE + bin];
    if (v) atomicAdd(&ghist[colBase * NBINS + i], v);
  }
}

// ---------------- fallback (no workspace): fp32-staged 128x128 tile -------
__global__ __launch_bounds__(256) void gemm_hist_fb(
    const float* __restrict__ xf, const float* __restrict__ wf,
    const float* __restrict__ mins, const float* __restrict__ maxs,
    int* __restrict__ ghist)
{
  __shared__ __align__(16) half_t ldsA[4096];
  __shared__ __align__(16) half_t ldsB[4096];
  __shared__ int shist[128 * HSTRIDE];

  const int t     = threadIdx.x;
  const int lane  = t & 63;
  const int wv    = t >> 6;
  const int waveM = wv >> 1;
  const int waveN = wv & 1;
  const int l16   = lane & 15;
  const int quad  = lane >> 4;
  const int colBase = blockIdx.x * 128;

  for (int i = t; i < 128 * HSTRIDE; i += 256) shist[i] = 0;

  float mn[4], mx[4], inv[4];
  int lcol[4];
#pragma unroll
  for (int nt = 0; nt < 4; ++nt) {
    int lc = waveN * 64 + nt * 16 + l16;
    lcol[nt] = lc;
    float a = mins[colBase + lc], b = maxs[colBase + lc];
    mn[nt] = a; mx[nt] = b;
    inv[nt] = (float)NBINS / (b - a);
  }

  int aOff[4], bOff[4];
#pragma unroll
  for (int mt = 0; mt < 4; ++mt) {
    int m = waveM * 64 + mt * 16 + l16;
    aOff[mt] = (m * 4 + (quad ^ ((m >> 1) & 3))) * 8;
  }
#pragma unroll
  for (int nt = 0; nt < 4; ++nt) {
    int n = waveN * 64 + nt * 16 + l16;
    bOff[nt] = (n * 4 + (quad ^ ((n >> 1) & 3))) * 8;
  }

  for (int rt = blockIdx.y; rt < S_DIM / 128; rt += gridDim.y) {
    const int rowBase = rt * 128;
    f32x4 acc[4][4];
#pragma unroll
    for (int mt = 0; mt < 4; ++mt)
#pragma unroll
      for (int nt = 0; nt < 4; ++nt) acc[mt][nt] = (f32x4){0.f, 0.f, 0.f, 0.f};

    for (int kt = 0; kt < K_DIM; kt += 32) {
      __syncthreads();
#pragma unroll
      for (int i = 0; i < 2; ++i) {
        const int seg = t + i * 256;
        const int row = seg >> 2;
        const int kch = (seg & 3) ^ ((row >> 1) & 3);
        const float* ga = xf + (size_t)(rowBase + row) * K_DIM + kt + kch * 8;
        float4 v0 = ((const float4*)ga)[0];
        float4 v1 = ((const float4*)ga)[1];
        half8 h = { (half_t)v0.x, (half_t)v0.y, (half_t)v0.z, (half_t)v0.w,
                    (half_t)v1.x, (half_t)v1.y, (half_t)v1.z, (half_t)v1.w };
        *(half8*)&ldsA[seg * 8] = h;
        const float* gb = wf + (size_t)(colBase + row) * K_DIM + kt + kch * 8;
        float4 u0 = ((const float4*)gb)[0];
        float4 u1 = ((const float4*)gb)[1];
        half8 g = { (half_t)u0.x, (half_t)u0.y, (half_t)u0.z, (half_t)u0.w,
                    (half_t)u1.x, (half_t)u1.y, (half_t)u1.z, (half_t)u1.w };
        *(half8*)&ldsB[seg * 8] = g;
      }
      __syncthreads();
      {
        half8 aFf[4], bFf[4];
#pragma unroll
        for (int mt = 0; mt < 4; ++mt) aFf[mt] = *(const half8*)&ldsA[aOff[mt]];
#pragma unroll
        for (int nt = 0; nt < 4; ++nt) bFf[nt] = *(const half8*)&ldsB[bOff[nt]];
#pragma unroll
        for (int mt = 0; mt < 4; ++mt)
#pragma unroll
          for (int nt = 0; nt < 4; ++nt)
            acc[mt][nt] = __builtin_amdgcn_mfma_f32_16x16x32_f16(
                aFf[mt], bFf[nt], acc[mt][nt], 0, 0, 0);
      }
    }

#pragma unroll
    for (int nt = 0; nt < 4; ++nt) {
      const float a = mn[nt], b = mx[nt], sc = inv[nt];
      int* colHist = &shist[lcol[nt] * HSTRIDE];
#pragma unroll
      for (int mt = 0; mt < 4; ++mt) {
#pragma unroll
        for (int r = 0; r < 4; ++r) {
          float v = acc[mt][nt][r];
          if (v >= a && v <= b) {
            int bin = (int)((v - a) * sc);
            bin = bin > NBINS - 1 ? NBINS - 1 : bin;
            atomicAdd(&colHist[bin], 1);
          }
        }
      }
    }
  }

  __syncthreads();
  for (int i = t; i < 128 * NBINS; i += 256) {
    int col = i / NBINS, bin = i - col * NBINS;
    int v = shist[col * HSTRIDE + bin];
    if (v) atomicAdd(&ghist[colBase * NBINS + i], v);
  }
}

// ---------------- L2 normalize per group of 20 bins (in place) ------------
__global__ void normalize_kernel(const int* __restrict__ hist, float* __restrict__ out) {
  int g = blockIdx.x * blockDim.x + threadIdx.x;
  if (g >= D_DIM) return;
  const int base = g * NBINS;
  float v[NBINS];
  float ss = 0.f;
#pragma unroll
  for (int i = 0; i < NBINS; ++i) { v[i] = (float)hist[base + i]; ss += v[i] * v[i]; }
  float sc = 1.0f / fmaxf(sqrtf(ss), 1e-12f);
#pragma unroll
  for (int i = 0; i < NBINS; ++i) out[base + i] = v[i] * sc;
}

extern "C" void kernel_launch(void* const* d_in, const int* in_sizes, int n_in,
                              void* d_out, int out_size, void* d_ws, size_t ws_size,
                              hipStream_t stream) {
  const float* x    = (const float*)d_in[0];
  const float* W    = (const float*)d_in[1];
  const float* mins = (const float*)d_in[2];
  const float* maxs = (const float*)d_in[3];
  float* out = (float*)d_out;

  const size_t xh_elems = (size_t)S_DIM * K_DIM;
  const size_t wh_elems = (size_t)D_DIM * K_DIM;
  const size_t need = (xh_elems + wh_elems) * sizeof(half_t);

  if (ws_size >= need) {
    half_t* xh = (half_t*)d_ws;
    half_t* wh = xh + xh_elems;
    int n8x = (int)(xh_elems / 8), n8w = (int)(wh_elems / 8);
    int tot = n8x + n8w;
    // cvt also zeroes d_out (re-poisoned 0xAA between runs)
    cvt_f32_f16<<<(tot + 255) / 256, 256, 0, stream>>>(
        x, xh, n8x, W, wh, n8w, (float4*)d_out, out_size / 4);
    gemm_hist256<<<dim3(1600), 1024, 0, stream>>>(xh, wh, mins, maxs, (int*)d_out);
  } else {
    hipMemsetAsync(d_out, 0, (size_t)out_size * sizeof(float), stream);
    gemm_hist_fb<<<dim3(D_DIM / 128, 64), 256, 0, stream>>>(
        x, W, mins, maxs, (int*)d_out);
  }

  normalize_kernel<<<(D_DIM + 255) / 256, 256, 0, stream>>>((int*)d_out, out);
}

// Round 8
// 366.633 us; speedup vs baseline: 1.0369x; 1.0369x over previous
//
#include <hip/hip_runtime.h>
#include <cmath>

// Problem constants: S=16384, IN_DIM=1024, D=6400, BINS=20
#define S_DIM 16384
#define K_DIM 1024
#define D_DIM 6400
#define NBINS 20
#define HSTRIDE 21   // shist column stride (pad 20->21: spreads banks)

using half_t = _Float16;
using half8  = __attribute__((ext_vector_type(8))) _Float16;
using f32x4  = __attribute__((ext_vector_type(4))) float;

// ---------------- fp32 -> fp16 convert + d_out zeroing (one launch) -------
__global__ void cvt_f32_f16(const float* __restrict__ a, half_t* __restrict__ da, int n8a,
                            const float* __restrict__ b, half_t* __restrict__ db, int n8b,
                            float4* __restrict__ z, int nz4) {
  int i = blockIdx.x * blockDim.x + threadIdx.x;
  if (i < nz4) z[i] = (float4){0.f, 0.f, 0.f, 0.f};   // histogram accumulator
  const float* s; half_t* d; int idx;
  if (i < n8a) { s = a; d = da; idx = i; }
  else { idx = i - n8a; if (idx >= n8b) return; s = b; d = db; }
  float4 v0 = ((const float4*)s)[idx * 2];
  float4 v1 = ((const float4*)s)[idx * 2 + 1];
  half8 h = { (half_t)v0.x, (half_t)v0.y, (half_t)v0.z, (half_t)v0.w,
              (half_t)v1.x, (half_t)v1.y, (half_t)v1.z, (half_t)v1.w };
  ((half8*)d)[idx] = h;
}

#define VMWAIT0() __asm__ volatile("s_waitcnt vmcnt(0)" ::: "memory")
#define BAR()     __asm__ volatile("s_barrier" ::: "memory")
#define SP1()     __builtin_amdgcn_s_setprio(1)
#define SP0()     __builtin_amdgcn_s_setprio(0)

#define GLL(SRC, DST) __builtin_amdgcn_global_load_lds(                      \
    (const __attribute__((address_space(1))) void*)(SRC),                    \
    (__attribute__((address_space(3))) void*)(DST), 16, 0, 0)

// ------- fused GEMM + histogram, 256x256, 16-wave, BK=64, 16-MFMA clusters
// 1024 threads = 16 waves (4M x 4N); per-wave C = 64x64; BK=64; 16 K-tiles.
// R7 post-mortem: MFMA pipe (1240 cyc/BK32-tile/CU) and LDS-read pipe
// (~1540) ran ADDITIVELY (wall 3060) because 4-MFMA clusters between
// lgkm-dependent reads + lockstep barriers idle one pipe while the other
// runs.  Fix = m201's signature: 16-MFMA clusters per wait.  Per tile:
//   [BAR from prev tile]  stage {A,B}(t+1) -> buf[(t+1)&1]   (4 GLL)
//   ph0: read 8 frags (ks=0: 4 A + 4 B b128) ; SP1 16 MFMA SP0
//   ph1: read 8 frags (ks=1)                 ; SP1 16 MFMA SP0
//   VMWAIT0 ; BAR
// One barrier + one vmcnt wait per BK=64 (was 4 barriers + 2 waits per
// BK=64-equivalent).  A 16-MFMA cluster = ~620 cyc/SIMD -> covers the other
// waves' read bursts; compiler emits fine lgkmcnt(N) for the JIT frag reads.
// RAW: tile t's data staged during t-1, retired by VMWAIT0 + published by
// BAR at t-1's end (issue-to-wait ~1 tile >> 900-cyc HBM latency -> no
// stall; all-zero waits also immune to unrelated VMEM ops in the ledger).
// WAR: stage at t overwrites buf[(t+1)&1], last read by t-1; every wave's
// t-1 reads are lgkm-retired before its pre-barrier MFMAs -> done before
// any wave passes the barrier and issues the stage.
// LDS swizzle (128B rows, 8x16B chunks): LDS[r][c] = G[r][c^(r&7)].
// Store side: GLL dest linear (slot t*16), source chunk (t&7)^((t>>3)&7).
// Read side: chunk (4ks+quad)^(l16&7) -> each 8-lane group hits all 32
// banks exactly once; wave64 = 2 lanes/bank = free.  (row&7 == l16&7 since
// wm*64, mf*16 are multiples of 16.)  Operand (row,k) mapping identical to
// refcheck-passing R7: k = ks*32 + quad*8 + j, row = w*64 + f*16 + l16.
__global__ __launch_bounds__(1024, 4) void gemm_hist256(
    const half_t* __restrict__ xh, const half_t* __restrict__ wh,
    const float* __restrict__ mins, const float* __restrict__ maxs,
    int* __restrict__ ghist)
{
  __shared__ __align__(16) char ldsA[2 * 32768];   // 2 bufs x 256 rows x 128 B
  __shared__ __align__(16) char ldsB[2 * 32768];
  __shared__ int shist[256 * HSTRIDE];             // 21.5 KB (total 152.6 KB)

  const int t    = threadIdx.x;
  const int lane = t & 63;
  const int wv   = t >> 6;           // 0..15
  const int wm   = wv >> 2;          // 0..3
  const int wn   = wv & 3;           // 0..3
  const int l16  = lane & 15;
  const int quad = lane >> 4;

  // XCD-aware bijective swizzle: 1600 blocks = 8 XCDs x 200
  const int bid = blockIdx.x;
  const int wg  = (bid & 7) * 200 + (bid >> 3);
  const int ct  = wg / 64;                 // 0..24 col-tiles
  const int rt  = wg - ct * 64;            // 0..63 row-tiles
  const int colBase = ct * 256;
  const int rowBase = rt * 256;

  for (int i = t; i < 256 * HSTRIDE; i += 1024) shist[i] = 0;

  // Fragment read bases, one per ks (k-slice of 32).  Row stride 128 B.
  // chunk(ks) = (4*ks + quad) ^ (l16 & 7).
  const char* pA0 = ldsA + (wm * 64 + l16) * 128 + (((0 + quad) ^ (l16 & 7)) * 16);
  const char* pA1 = ldsA + (wm * 64 + l16) * 128 + (((4 + quad) ^ (l16 & 7)) * 16);
  const char* pB0 = ldsB + (wn * 64 + l16) * 128 + (((0 + quad) ^ (l16 & 7)) * 16);
  const char* pB1 = ldsB + (wn * 64 + l16) * 128 + (((4 + quad) ^ (l16 & 7)) * 16);

  // Staging: thread t owns linear 16B slot t of each 16KB half (rows 0-127);
  // second GLL covers rows 128-255.  Source chunk = (t&7)^((t>>3)&7).
  const int gOff = (t >> 3) * K_DIM + (((t & 7) ^ ((t >> 3) & 7)) * 8);  // elems
  const int wvD  = wv * 1024;   // wave-uniform LDS base (HW adds lane*16)

  const half_t* xS = xh + (size_t)rowBase * K_DIM + gOff;
  const half_t* wS = wh + (size_t)colBase * K_DIM + gOff;

  f32x4 acc[4][4];
#pragma unroll
  for (int m = 0; m < 4; ++m)
#pragma unroll
    for (int n = 0; n < 4; ++n) acc[m][n] = (f32x4){0.f, 0.f, 0.f, 0.f};

  half8 aF[4], bF[4];

#define MFMA16()                                                             \
  _Pragma("unroll") for (int mf = 0; mf < 4; ++mf)                           \
  _Pragma("unroll") for (int nf = 0; nf < 4; ++nf)                           \
    acc[mf][nf] = __builtin_amdgcn_mfma_f32_16x16x32_f16(                    \
        aF[mf], bF[nf], acc[mf][nf], 0, 0, 0);

  // Prologue: stage tile 0 -> buf0 (4 GLL); retire + publish.
  GLL(xS,          ldsA + wvD);
  GLL(xS + 131072, ldsA + 16384 + wvD);   // +128 rows (128*1024 elems)
  GLL(wS,          ldsB + wvD);
  GLL(wS + 131072, ldsB + 16384 + wvD);
  VMWAIT0(); BAR();

  // Loop-carried staging pointers: at tile t they point at k-offset
  // (t+1)*64 elements; advance +64 per tile.
  const half_t* xStg = xS + 64;
  const half_t* wStg = wS + 64;

  // PB = current tile's buf offset, PN = next tile's.  STG: stage t+1.
#define TILE(PB, PN, STG)                                                    \
  {                                                                          \
    if (STG) {                                                               \
      GLL(xStg,          ldsA + (PN) + wvD);                                 \
      GLL(xStg + 131072, ldsA + (PN) + 16384 + wvD);                         \
      GLL(wStg,          ldsB + (PN) + wvD);                                 \
      GLL(wStg + 131072, ldsB + (PN) + 16384 + wvD);                         \
      xStg += 64; wStg += 64;                                                \
    }                                                                        \
    _Pragma("unroll") for (int mf = 0; mf < 4; ++mf)                         \
      aF[mf] = *(const half8*)(pA0 + (PB) + mf * 2048);                      \
    _Pragma("unroll") for (int nf = 0; nf < 4; ++nf)                         \
      bF[nf] = *(const half8*)(pB0 + (PB) + nf * 2048);                      \
    SP1(); MFMA16(); SP0();                                                  \
    _Pragma("unroll") for (int mf = 0; mf < 4; ++mf)                         \
      aF[mf] = *(const half8*)(pA1 + (PB) + mf * 2048);                      \
    _Pragma("unroll") for (int nf = 0; nf < 4; ++nf)                         \
      bF[nf] = *(const half8*)(pB1 + (PB) + nf * 2048);                      \
    SP1(); MFMA16(); SP0();                                                  \
    VMWAIT0(); BAR();                                                        \
  }

  // 16 K-tiles; tiles 0..14 stage t+1, tile 15 computes only.
#pragma unroll 1
  for (int it = 0; it < 7; ++it) {
    TILE(0,     32768, 1);
    TILE(32768, 0,     1);
  }
  TILE(0,     32768, 1);   // t=14 (stages 15)
  TILE(32768, 0,     0);   // t=15

#undef TILE

  // Epilogue: bin 64 values/thread. torch.histc semantics: count iff
  // min<=v<=max; v==max -> last bin (trunc==floor since v-a>=0).
#pragma unroll
  for (int nf = 0; nf < 4; ++nf) {
    const int lc = wn * 64 + nf * 16 + l16;
    const float a = mins[colBase + lc], b = maxs[colBase + lc];
    const float sc = (float)NBINS / (b - a);
    int* colHist = &shist[lc * HSTRIDE];
#pragma unroll
    for (int mf = 0; mf < 4; ++mf) {
#pragma unroll
      for (int r = 0; r < 4; ++r) {
        float v = acc[mf][nf][r];
        if (v >= a && v <= b) {
          int bin = (int)((v - a) * sc);
          bin = bin > NBINS - 1 ? NBINS - 1 : bin;
          atomicAdd(&colHist[bin], 1);
        }
      }
    }
  }
  __syncthreads();
  for (int i = t; i < 256 * NBINS; i += 1024) {
    int col = i / NBINS, bin = i - col * NBINS;
    int v = shist[col * HSTRIDE + bin];
    if (v) atomicAdd(&ghist[colBase * NBINS + i], v);
  }
}

// ---------------- fallback (no workspace): fp32-staged 128x128 tile -------
__global__ __launch_bounds__(256) void gemm_hist_fb(
    const float* __restrict__ xf, const float* __restrict__ wf,
    const float* __restrict__ mins, const float* __restrict__ maxs,
    int* __restrict__ ghist)
{
  __shared__ __align__(16) half_t ldsA[4096];
  __shared__ __align__(16) half_t ldsB[4096];
  __shared__ int shist[128 * HSTRIDE];

  const int t     = threadIdx.x;
  const int lane  = t & 63;
  const int wv    = t >> 6;
  const int waveM = wv >> 1;
  const int waveN = wv & 1;
  const int l16   = lane & 15;
  const int quad  = lane >> 4;
  const int colBase = blockIdx.x * 128;

  for (int i = t; i < 128 * HSTRIDE; i += 256) shist[i] = 0;

  float mn[4], mx[4], inv[4];
  int lcol[4];
#pragma unroll
  for (int nt = 0; nt < 4; ++nt) {
    int lc = waveN * 64 + nt * 16 + l16;
    lcol[nt] = lc;
    float a = mins[colBase + lc], b = maxs[colBase + lc];
    mn[nt] = a; mx[nt] = b;
    inv[nt] = (float)NBINS / (b - a);
  }

  int aOff[4], bOff[4];
#pragma unroll
  for (int mt = 0; mt < 4; ++mt) {
    int m = waveM * 64 + mt * 16 + l16;
    aOff[mt] = (m * 4 + (quad ^ ((m >> 1) & 3))) * 8;
  }
#pragma unroll
  for (int nt = 0; nt < 4; ++nt) {
    int n = waveN * 64 + nt * 16 + l16;
    bOff[nt] = (n * 4 + (quad ^ ((n >> 1) & 3))) * 8;
  }

  for (int rt = blockIdx.y; rt < S_DIM / 128; rt += gridDim.y) {
    const int rowBase = rt * 128;
    f32x4 acc[4][4];
#pragma unroll
    for (int mt = 0; mt < 4; ++mt)
#pragma unroll
      for (int nt = 0; nt < 4; ++nt) acc[mt][nt] = (f32x4){0.f, 0.f, 0.f, 0.f};

    for (int kt = 0; kt < K_DIM; kt += 32) {
      __syncthreads();
#pragma unroll
      for (int i = 0; i < 2; ++i) {
        const int seg = t + i * 256;
        const int row = seg >> 2;
        const int kch = (seg & 3) ^ ((row >> 1) & 3);
        const float* ga = xf + (size_t)(rowBase + row) * K_DIM + kt + kch * 8;
        float4 v0 = ((const float4*)ga)[0];
        float4 v1 = ((const float4*)ga)[1];
        half8 h = { (half_t)v0.x, (half_t)v0.y, (half_t)v0.z, (half_t)v0.w,
                    (half_t)v1.x, (half_t)v1.y, (half_t)v1.z, (half_t)v1.w };
        *(half8*)&ldsA[seg * 8] = h;
        const float* gb = wf + (size_t)(colBase + row) * K_DIM + kt + kch * 8;
        float4 u0 = ((const float4*)gb)[0];
        float4 u1 = ((const float4*)gb)[1];
        half8 g = { (half_t)u0.x, (half_t)u0.y, (half_t)u0.z, (half_t)u0.w,
                    (half_t)u1.x, (half_t)u1.y, (half_t)u1.z, (half_t)u1.w };
        *(half8*)&ldsB[seg * 8] = g;
      }
      __syncthreads();
      {
        half8 aFf[4], bFf[4];
#pragma unroll
        for (int mt = 0; mt < 4; ++mt) aFf[mt] = *(const half8*)&ldsA[aOff[mt]];
#pragma unroll
        for (int nt = 0; nt < 4; ++nt) bFf[nt] = *(const half8*)&ldsB[bOff[nt]];
#pragma unroll
        for (int mt = 0; mt < 4; ++mt)
#pragma unroll
          for (int nt = 0; nt < 4; ++nt)
            acc[mt][nt] = __builtin_amdgcn_mfma_f32_16x16x32_f16(
                aFf[mt], bFf[nt], acc[mt][nt], 0, 0, 0);
      }
    }

#pragma unroll
    for (int nt = 0; nt < 4; ++nt) {
      const float a = mn[nt], b = mx[nt], sc = inv[nt];
      int* colHist = &shist[lcol[nt] * HSTRIDE];
#pragma unroll
      for (int mt = 0; mt < 4; ++mt) {
#pragma unroll
        for (int r = 0; r < 4; ++r) {
          float v = acc[mt][nt][r];
          if (v >= a && v <= b) {
            int bin = (int)((v - a) * sc);
            bin = bin > NBINS - 1 ? NBINS - 1 : bin;
            atomicAdd(&colHist[bin], 1);
          }
        }
      }
    }
  }

  __syncthreads();
  for (int i = t; i < 128 * NBINS; i += 256) {
    int col = i / NBINS, bin = i - col * NBINS;
    int v = shist[col * HSTRIDE + bin];
    if (v) atomicAdd(&ghist[colBase * NBINS + i], v);
  }
}

// ---------------- L2 normalize per group of 20 bins (in place) ------------
__global__ void normalize_kernel(const int* __restrict__ hist, float* __restrict__ out) {
  int g = blockIdx.x * blockDim.x + threadIdx.x;
  if (g >= D_DIM) return;
  const int base = g * NBINS;
  float v[NBINS];
  float ss = 0.f;
#pragma unroll
  for (int i = 0; i < NBINS; ++i) { v[i] = (float)hist[base + i]; ss += v[i] * v[i]; }
  float sc = 1.0f / fmaxf(sqrtf(ss), 1e-12f);
#pragma unroll
  for (int i = 0; i < NBINS; ++i) out[base + i] = v[i] * sc;
}

extern "C" void kernel_launch(void* const* d_in, const int* in_sizes, int n_in,
                              void* d_out, int out_size, void* d_ws, size_t ws_size,
                              hipStream_t stream) {
  const float* x    = (const float*)d_in[0];
  const float* W    = (const float*)d_in[1];
  const float* mins = (const float*)d_in[2];
  const float* maxs = (const float*)d_in[3];
  float* out = (float*)d_out;

  const size_t xh_elems = (size_t)S_DIM * K_DIM;
  const size_t wh_elems = (size_t)D_DIM * K_DIM;
  const size_t need = (xh_elems + wh_elems) * sizeof(half_t);

  if (ws_size >= need) {
    half_t* xh = (half_t*)d_ws;
    half_t* wh = xh + xh_elems;
    int n8x = (int)(xh_elems / 8), n8w = (int)(wh_elems / 8);
    int tot = n8x + n8w;
    // cvt also zeroes d_out (re-poisoned 0xAA between runs)
    cvt_f32_f16<<<(tot + 255) / 256, 256, 0, stream>>>(
        x, xh, n8x, W, wh, n8w, (float4*)d_out, out_size / 4);
    gemm_hist256<<<dim3(1600), 1024, 0, stream>>>(xh, wh, mins, maxs, (int*)d_out);
  } else {
    hipMemsetAsync(d_out, 0, (size_t)out_size * sizeof(float), stream);
    gemm_hist_fb<<<dim3(D_DIM / 128, 64), 256, 0, stream>>>(
        x, W, mins, maxs, (int*)d_out);
  }

  normalize_kernel<<<(D_DIM + 255) / 256, 256, 0, stream>>>((int*)d_out, out);
}